// Round 5
// baseline (2031.998 us; speedup 1.0000x reference)
//
#include <hip/hip_runtime.h>

typedef unsigned short ushort_t;
typedef __attribute__((ext_vector_type(4))) float f32x4;
typedef __attribute__((ext_vector_type(8))) short short8;

__device__ __forceinline__ ushort_t f2bf(float f) {
  union { float f; unsigned u; } v; v.f = f;
  unsigned r = v.u + 0x7fffu + ((v.u >> 16) & 1u);
  return (ushort_t)(r >> 16);
}

// ---------------- kernel 0a: weights fp32 -> bf16 (wq,wk,wv,wo concatenated) ----
__global__ __launch_bounds__(256) void cvt_w_k(const float* __restrict__ wq,
                                               const float* __restrict__ wk,
                                               const float* __restrict__ wv,
                                               const float* __restrict__ wo,
                                               ushort_t* __restrict__ dst) {
  int idx = (blockIdx.x * 256 + threadIdx.x) * 4;  // 0 .. 1048572
  int m = idx >> 18;
  int off = idx & 0x3ffff;
  const float* s = (m == 0) ? wq : (m == 1) ? wk : (m == 2) ? wv : wo;
  float4 v = *(const float4*)(s + off);
  ushort4 o;
  o.x = f2bf(v.x); o.y = f2bf(v.y); o.z = f2bf(v.z); o.w = f2bf(v.w);
  *(ushort4*)(dst + idx) = o;
}

// ---------------- kernel 0b: x (b,c,192,192) fp32 -> xT[token][c] bf16 (chunk) --
__global__ __launch_bounds__(256) void xpose_k(const float* __restrict__ x,
                                               ushort_t* __restrict__ xT, int b0) {
  __shared__ ushort_t tile[128 * 80];  // [c_local][token], padded to 80
  int bid = blockIdx.x;                // nwin_chunk * 4 c-chunks
  int winl = bid >> 2, kc = bid & 3;
  int b = b0 + winl / 576, rem = winl % 576, wh = rem / 24, ww = rem % 24;
  int tid = threadIdx.x;
  {
    int c_l = tid >> 1, half = tid & 1;
    const float* xb = x + ((((size_t)b * 512 + kc * 128 + c_l) * 192 + wh * 8) * 192 + ww * 8);
#pragma unroll
    for (int ii = 0; ii < 4; ++ii) {
      int i = half * 4 + ii;
      float4 v0 = *(const float4*)(xb + i * 192);
      float4 v1 = *(const float4*)(xb + i * 192 + 4);
      uint4 u;
      u.x = (unsigned)f2bf(v0.x) | ((unsigned)f2bf(v0.y) << 16);
      u.y = (unsigned)f2bf(v0.z) | ((unsigned)f2bf(v0.w) << 16);
      u.z = (unsigned)f2bf(v1.x) | ((unsigned)f2bf(v1.y) << 16);
      u.w = (unsigned)f2bf(v1.z) | ((unsigned)f2bf(v1.w) << 16);
      *(uint4*)&tile[c_l * 80 + i * 8] = u;
    }
  }
  __syncthreads();
  {
    int tok = tid >> 2, q = tid & 3;
    unsigned w[16];
#pragma unroll
    for (int k = 0; k < 16; ++k) {
      unsigned lo = tile[(q * 32 + 2 * k) * 80 + tok];
      unsigned hi = tile[(q * 32 + 2 * k + 1) * 80 + tok];
      w[k] = lo | (hi << 16);
    }
    ushort_t* d = xT + ((size_t)(winl * 64 + tok) * 512 + kc * 128 + q * 32);
#pragma unroll
    for (int s2 = 0; s2 < 4; ++s2) {
      uint4 u; u.x = w[s2 * 4 + 0]; u.y = w[s2 * 4 + 1]; u.z = w[s2 * 4 + 2]; u.w = w[s2 * 4 + 3];
      *(uint4*)(d + s2 * 8) = u;
    }
  }
}

// ---------------- kernel 1: QKV GEMM  Og[t][1536] = xT[t][512] . concat(wq,wk,wv)^T
// 128x128 tile, BK=64, 256 thr (4 waves 2x2). 2-phase staging (no reg prefetch ->
// no VGPR spill; round-4 post-mortem: spill scratch caused 2.5 GB write-amp).
__global__ __launch_bounds__(256) void qkv_k(const ushort_t* __restrict__ xT,
                                             const ushort_t* __restrict__ wB,
                                             ushort_t* __restrict__ Og) {
  __shared__ __align__(16) ushort_t smem[2 * 128 * 72];  // As | Bs ; reused as Ct[128][136]
  ushort_t* As = smem;
  ushort_t* Bs = smem + 128 * 72;
  int bid = blockIdx.x;
  int cwg = gridDim.x >> 3;                       // grid % 8 == 0
  int wg = (bid & 7) * cwg + (bid >> 3);          // XCD-chunked swizzle
  int mt = wg / 12, nt = wg % 12;                 // consecutive wg share A-tile
  int t0 = mt * 128;
  int tid = threadIdx.x, lane = tid & 63, wid = tid >> 6;
  int wr = wid >> 1, wc = wid & 1;
  int l15 = lane & 15, l4 = lane >> 4;
  const ushort_t* Bsrc = wB + (size_t)(nt * 128) * 512;  // rows of concat(wq,wk,wv)

  const f32x4 z = {0.f, 0.f, 0.f, 0.f};
  f32x4 acc[4][4];
#pragma unroll
  for (int i = 0; i < 4; ++i)
#pragma unroll
    for (int j = 0; j < 4; ++j) acc[i][j] = z;

  int srow[4], sslot[4];
#pragma unroll
  for (int c = 0; c < 4; ++c) { int u = c * 256 + tid; srow[c] = u >> 3; sslot[c] = u & 7; }

  for (int ks = 0; ks < 8; ++ks) {
    int ko = ks * 64;
    uint4 ta[4], tb[4];
#pragma unroll
    for (int c = 0; c < 4; ++c) {
      ta[c] = *(const uint4*)&xT[(size_t)(t0 + srow[c]) * 512 + ko + sslot[c] * 8];
      tb[c] = *(const uint4*)&Bsrc[(size_t)srow[c] * 512 + ko + sslot[c] * 8];
    }
    __syncthreads();  // previous compute done; LDS free
#pragma unroll
    for (int c = 0; c < 4; ++c) {
      *(uint4*)&As[srow[c] * 72 + sslot[c] * 8] = ta[c];
      *(uint4*)&Bs[srow[c] * 72 + sslot[c] * 8] = tb[c];
    }
    __syncthreads();  // tiles ready
#pragma unroll
    for (int kk = 0; kk < 2; ++kk) {
      short8 aF[4], bF[4];
#pragma unroll
      for (int mi = 0; mi < 4; ++mi)
        aF[mi] = *(const short8*)&As[(wr * 64 + mi * 16 + l15) * 72 + kk * 32 + l4 * 8];
#pragma unroll
      for (int ni = 0; ni < 4; ++ni)
        bF[ni] = *(const short8*)&Bs[(wc * 64 + ni * 16 + l15) * 72 + kk * 32 + l4 * 8];
#pragma unroll
      for (int mi = 0; mi < 4; ++mi)
#pragma unroll
        for (int ni = 0; ni < 4; ++ni)
          acc[mi][ni] = __builtin_amdgcn_mfma_f32_16x16x32_bf16(aF[mi], bF[ni], acc[mi][ni], 0, 0, 0);
    }
  }
  // ---- epilogue: C tile -> LDS bf16 [128][136] -> coalesced 256B row segments ----
  __syncthreads();
  ushort_t* Ct = smem;
#pragma unroll
  for (int mi = 0; mi < 4; ++mi)
#pragma unroll
    for (int ni = 0; ni < 4; ++ni)
#pragma unroll
      for (int rr = 0; rr < 4; ++rr) {
        int row = wr * 64 + mi * 16 + l4 * 4 + rr;
        int col = wc * 64 + ni * 16 + l15;
        Ct[row * 136 + col] = f2bf(acc[mi][ni][rr]);
      }
  __syncthreads();
#pragma unroll
  for (int it = 0; it < 8; ++it) {
    int cidx = it * 256 + tid;
    int row = cidx >> 4, cc = (cidx & 15) * 8;
    uint4 u = *(const uint4*)&Ct[row * 136 + cc];
    *(uint4*)&Og[(size_t)(t0 + row) * 1536 + nt * 128 + cc] = u;
  }
}

// ---------------- kernel 2: per-(window,head) attention, QKV from global --------
__global__ __launch_bounds__(256) void attn2_k(const ushort_t* __restrict__ Og,
                                               const float* __restrict__ beta,
                                               ushort_t* __restrict__ O) {
  __shared__ ushort_t qS[64 * 72], kS[64 * 72], vT[64 * 72], pS[64 * 72];
  int bid = blockIdx.x;             // winl*8 + h
  int winl = bid >> 3, h = bid & 7;
  int t0 = winl * 64;
  int tid = threadIdx.x, lane = tid & 63, wid = tid >> 6;
  int l15 = lane & 15, l4 = lane >> 4;

  {
    int m = tid & 63, dg = tid >> 6;
    const ushort_t* base = Og + (size_t)(t0 + m) * 1536 + h * 64 + dg * 16;
    uint4 vq0 = *(const uint4*)(base);
    uint4 vq1 = *(const uint4*)(base + 8);
    uint4 vk0 = *(const uint4*)(base + 512);
    uint4 vk1 = *(const uint4*)(base + 520);
    uint4 vv0 = *(const uint4*)(base + 1024);
    uint4 vv1 = *(const uint4*)(base + 1032);
    *(uint4*)&qS[m * 72 + dg * 16] = vq0;
    *(uint4*)&qS[m * 72 + dg * 16 + 8] = vq1;
    *(uint4*)&kS[m * 72 + dg * 16] = vk0;
    *(uint4*)&kS[m * 72 + dg * 16 + 8] = vk1;
    int dbase = (dg * 16) * 72 + m;
#define VW(word, j0) \
    vT[dbase + (j0) * 72] = (ushort_t)((word) & 0xffffu); \
    vT[dbase + ((j0) + 1) * 72] = (ushort_t)((word) >> 16);
    VW(vv0.x, 0) VW(vv0.y, 2) VW(vv0.z, 4) VW(vv0.w, 6)
    VW(vv1.x, 8) VW(vv1.y, 10) VW(vv1.z, 12) VW(vv1.w, 14)
#undef VW
  }
  __syncthreads();

  const f32x4 z = {0.f, 0.f, 0.f, 0.f};
  f32x4 sA[4];
#pragma unroll
  for (int i = 0; i < 4; ++i) sA[i] = z;
#pragma unroll
  for (int kk = 0; kk < 2; ++kk) {
    short8 aF = *(const short8*)&qS[(wid * 16 + l15) * 72 + kk * 32 + l4 * 8];
#pragma unroll
    for (int mt = 0; mt < 4; ++mt) {
      short8 bF = *(const short8*)&kS[(mt * 16 + l15) * 72 + kk * 32 + l4 * 8];
      sA[mt] = __builtin_amdgcn_mfma_f32_16x16x32_bf16(aF, bF, sA[mt], 0, 0, 0);
    }
  }
  const float* betah = beta + h * 4096;
  float p[4][4];
  float rmax[4] = {-1e30f, -1e30f, -1e30f, -1e30f};
#pragma unroll
  for (int mt = 0; mt < 4; ++mt)
#pragma unroll
    for (int r = 0; r < 4; ++r) {
      int n = wid * 16 + l4 * 4 + r;
      float val = sA[mt][r] * 0.125f + betah[n * 64 + mt * 16 + l15];
      p[mt][r] = val;
      rmax[r] = fmaxf(rmax[r], val);
    }
#pragma unroll
  for (int m = 1; m <= 8; m <<= 1)
#pragma unroll
    for (int r = 0; r < 4; ++r) rmax[r] = fmaxf(rmax[r], __shfl_xor(rmax[r], m, 64));
  float rsum[4] = {0.f, 0.f, 0.f, 0.f};
#pragma unroll
  for (int mt = 0; mt < 4; ++mt)
#pragma unroll
    for (int r = 0; r < 4; ++r) {
      p[mt][r] = __expf(p[mt][r] - rmax[r]);
      rsum[r] += p[mt][r];
    }
#pragma unroll
  for (int m = 1; m <= 8; m <<= 1)
#pragma unroll
    for (int r = 0; r < 4; ++r) rsum[r] += __shfl_xor(rsum[r], m, 64);
  float rinv[4];
#pragma unroll
  for (int r = 0; r < 4; ++r) rinv[r] = 1.f / rsum[r];
#pragma unroll
  for (int mt = 0; mt < 4; ++mt)
#pragma unroll
    for (int r = 0; r < 4; ++r)
      pS[(wid * 16 + l4 * 4 + r) * 72 + mt * 16 + l15] = f2bf(p[mt][r] * rinv[r]);
  // wave-local: each wave reads back only its own 16 P-rows (same-wave DS ordering)

  f32x4 oA[4];
#pragma unroll
  for (int i = 0; i < 4; ++i) oA[i] = z;
#pragma unroll
  for (int kk = 0; kk < 2; ++kk) {
    short8 aF = *(const short8*)&pS[(wid * 16 + l15) * 72 + kk * 32 + l4 * 8];
#pragma unroll
    for (int dt = 0; dt < 4; ++dt) {
      short8 bF = *(const short8*)&vT[(dt * 16 + l15) * 72 + kk * 32 + l4 * 8];
      oA[dt] = __builtin_amdgcn_mfma_f32_16x16x32_bf16(aF, bF, oA[dt], 0, 0, 0);
    }
  }
#pragma unroll
  for (int dt = 0; dt < 4; ++dt)
#pragma unroll
    for (int r = 0; r < 4; ++r) {
      int n = wid * 16 + l4 * 4 + r;
      O[(size_t)(t0 + n) * 512 + h * 64 + dt * 16 + l15] = f2bf(oA[dt][r]);
    }
}

// ---------------- kernel 3: proj GEMM 64x256 tiles; full-line fp32 stores -------
// M=64 wo rows (mm 0..7), N=256 tokens = 4 ww-consecutive windows (nn).
// 2-phase staging (no reg prefetch -> no spill).
__global__ __launch_bounds__(256) void proj_k3(const ushort_t* __restrict__ O,
                                               const ushort_t* __restrict__ woB,
                                               const float* __restrict__ bo,
                                               float* __restrict__ out, int w0) {
  __shared__ __align__(16) char smem_raw[64 * 72 * 2 + 256 * 72 * 2];  // 46080 B
  ushort_t* As = (ushort_t*)smem_raw;            // [64][72]
  ushort_t* Bs = (ushort_t*)smem_raw + 64 * 72;  // [256][72]
  float* Ct = (float*)smem_raw;                  // [64][132] epilogue (33792 B)
  int bid = blockIdx.x;
  int cwg = gridDim.x >> 3;
  int wg = (bid & 7) * cwg + (bid >> 3);
  int nn = wg >> 3, mm = wg & 7;                 // consecutive wg share B-tile
  int tid = threadIdx.x, lane = tid & 63, wid = tid >> 6;  // wid = window-in-tile
  int l15 = lane & 15, l4 = lane >> 4;
  const ushort_t* Asrc = woB + (size_t)(mm * 64) * 512;
  const ushort_t* Bsrc = O + (size_t)(nn * 256) * 512;

  const f32x4 z = {0.f, 0.f, 0.f, 0.f};
  f32x4 acc[4][4];
#pragma unroll
  for (int i = 0; i < 4; ++i)
#pragma unroll
    for (int j = 0; j < 4; ++j) acc[i][j] = z;

  int arow[2], aslot[2];
#pragma unroll
  for (int c = 0; c < 2; ++c) { int u = c * 256 + tid; arow[c] = u >> 3; aslot[c] = u & 7; }
  int brow[8], bslot[8];
#pragma unroll
  for (int c = 0; c < 8; ++c) { int u = c * 256 + tid; brow[c] = u >> 3; bslot[c] = u & 7; }

  for (int ks = 0; ks < 8; ++ks) {
    int ko = ks * 64;
    uint4 ta[2], tb[8];
#pragma unroll
    for (int c = 0; c < 2; ++c)
      ta[c] = *(const uint4*)&Asrc[(size_t)arow[c] * 512 + ko + aslot[c] * 8];
#pragma unroll
    for (int c = 0; c < 8; ++c)
      tb[c] = *(const uint4*)&Bsrc[(size_t)brow[c] * 512 + ko + bslot[c] * 8];
    __syncthreads();
#pragma unroll
    for (int c = 0; c < 2; ++c) *(uint4*)&As[arow[c] * 72 + aslot[c] * 8] = ta[c];
#pragma unroll
    for (int c = 0; c < 8; ++c) *(uint4*)&Bs[brow[c] * 72 + bslot[c] * 8] = tb[c];
    __syncthreads();
#pragma unroll
    for (int kk = 0; kk < 2; ++kk) {
      short8 aF[4], bF[4];
#pragma unroll
      for (int mi = 0; mi < 4; ++mi)
        aF[mi] = *(const short8*)&As[(mi * 16 + l15) * 72 + kk * 32 + l4 * 8];
#pragma unroll
      for (int ni = 0; ni < 4; ++ni)
        bF[ni] = *(const short8*)&Bs[(wid * 64 + ni * 16 + l15) * 72 + kk * 32 + l4 * 8];
#pragma unroll
      for (int mi = 0; mi < 4; ++mi)
#pragma unroll
        for (int ni = 0; ni < 4; ++ni)
          acc[mi][ni] = __builtin_amdgcn_mfma_f32_16x16x32_bf16(aF[mi], bF[ni], acc[mi][ni], 0, 0, 0);
    }
  }
  // ---- epilogue: 2 passes over i-halves; LDS [o][ (i&3)*32 + w*8 + j ] fp32 ----
#pragma unroll
  for (int p = 0; p < 2; ++p) {
    __syncthreads();
#pragma unroll
    for (int mi = 0; mi < 4; ++mi)
#pragma unroll
      for (int nq = 0; nq < 2; ++nq)
#pragma unroll
        for (int rr = 0; rr < 4; ++rr) {
          int o = mi * 16 + l4 * 4 + rr;
          int i3 = nq * 2 + (l15 >> 3);
          int col = i3 * 32 + wid * 8 + (l15 & 7);
          Ct[o * 132 + col] = acc[mi][p * 2 + nq][rr];
        }
    __syncthreads();
#pragma unroll
    for (int it = 0; it < 8; ++it) {
      int cidx = it * 256 + tid;
      int o_l = cidx >> 5, c4 = cidx & 31;
      float4 v = *(const float4*)&Ct[o_l * 132 + c4 * 4];
      int o = mm * 64 + o_l;
      float bias = bo[o];
      int w = (c4 & 7) >> 1, j = (c4 & 1) * 4, i = p * 4 + (c4 >> 3);
      int win = w0 + nn * 4 + w;
      int b = win / 576, rem = win % 576, wh = rem / 24, ww = rem % 24;
      size_t addr = (((size_t)b * 512 + o) * 192 + wh * 8 + i) * 192 + ww * 8 + j;
      float4 r;
      r.x = v.x + bias; r.y = v.y + bias; r.z = v.z + bias; r.w = v.w + bias;
      *(float4*)&out[addr] = r;
    }
  }
}

extern "C" void kernel_launch(void* const* d_in, const int* in_sizes, int n_in,
                              void* d_out, int out_size, void* d_ws, size_t ws_size,
                              hipStream_t stream) {
  const float* x    = (const float*)d_in[0];
  const float* wq   = (const float*)d_in[1];
  const float* wk   = (const float*)d_in[2];
  const float* wv   = (const float*)d_in[3];
  const float* wo   = (const float*)d_in[4];
  const float* bo   = (const float*)d_in[5];
  const float* beta = (const float*)d_in[6];

  ushort_t* wB = (ushort_t*)d_ws;  // 2 MiB bf16 weights (wq,wk,wv,wo)
  cvt_w_k<<<1024, 256, 0, stream>>>(wq, wk, wv, wo, wB);

  int nchunk = (ws_size >= (size_t)606076928) ? 1 : 4;
  int nb = 4 / nchunk;
  int nwin = nb * 576;
  int Tc = nwin * 64;
  char* base = (char*)d_ws + (size_t)2097152;
  ushort_t* xT = (ushort_t*)base;                               // Tc*512*2
  ushort_t* Og = (ushort_t*)(base + (size_t)Tc * 512 * 2);      // Tc*1536*2
  ushort_t* O  = xT;                                            // reuse after qkv

  for (int ch = 0; ch < nchunk; ++ch) {
    int b0 = ch * nb;
    xpose_k<<<nwin * 4, 256, 0, stream>>>(x, xT, b0);
    qkv_k<<<(Tc / 128) * 12, 256, 0, stream>>>(xT, wB, Og);
    attn2_k<<<nwin * 8, 256, 0, stream>>>(Og, beta, O);
    proj_k3<<<(Tc / 256) * 8, 256, 0, stream>>>(O, wB + 3 * 262144, bo,
                                                (float*)d_out, b0 * 576);
  }
}

// Round 6
// 1173.965 us; speedup vs baseline: 1.7309x; 1.7309x over previous
//
#include <hip/hip_runtime.h>

typedef unsigned short ushort_t;
typedef __attribute__((ext_vector_type(4))) float f32x4;
typedef __attribute__((ext_vector_type(8))) short short8;

__device__ __forceinline__ ushort_t f2bf(float f) {
  union { float f; unsigned u; } v; v.f = f;
  unsigned r = v.u + 0x7fffu + ((v.u >> 16) & 1u);
  return (ushort_t)(r >> 16);
}

// ---------------- kernel 0a: weights fp32 -> bf16 (wq,wk,wv,wo concatenated) ----
__global__ __launch_bounds__(256) void cvt_w_k(const float* __restrict__ wq,
                                               const float* __restrict__ wk,
                                               const float* __restrict__ wv,
                                               const float* __restrict__ wo,
                                               ushort_t* __restrict__ dst) {
  int idx = (blockIdx.x * 256 + threadIdx.x) * 4;  // 0 .. 1048572
  int m = idx >> 18;
  int off = idx & 0x3ffff;
  const float* s = (m == 0) ? wq : (m == 1) ? wk : (m == 2) ? wv : wo;
  float4 v = *(const float4*)(s + off);
  ushort4 o;
  o.x = f2bf(v.x); o.y = f2bf(v.y); o.z = f2bf(v.z); o.w = f2bf(v.w);
  *(ushort4*)(dst + idx) = o;
}

// ---------------- kernel 0b: x (b,c,192,192) fp32 -> xT[token][c] bf16 ----------
__global__ __launch_bounds__(256) void xpose_k(const float* __restrict__ x,
                                               ushort_t* __restrict__ xT) {
  __shared__ ushort_t tile[128 * 80];  // [c_local][token], padded to 80
  int bid = blockIdx.x;                // 2304 windows * 4 c-chunks
  int win = bid >> 2, kc = bid & 3;
  int b = win / 576, rem = win % 576, wh = rem / 24, ww = rem % 24;
  int tid = threadIdx.x;
  {
    int c_l = tid >> 1, half = tid & 1;
    const float* xb = x + ((((size_t)b * 512 + kc * 128 + c_l) * 192 + wh * 8) * 192 + ww * 8);
#pragma unroll
    for (int ii = 0; ii < 4; ++ii) {
      int i = half * 4 + ii;
      float4 v0 = *(const float4*)(xb + i * 192);
      float4 v1 = *(const float4*)(xb + i * 192 + 4);
      uint4 u;
      u.x = (unsigned)f2bf(v0.x) | ((unsigned)f2bf(v0.y) << 16);
      u.y = (unsigned)f2bf(v0.z) | ((unsigned)f2bf(v0.w) << 16);
      u.z = (unsigned)f2bf(v1.x) | ((unsigned)f2bf(v1.y) << 16);
      u.w = (unsigned)f2bf(v1.z) | ((unsigned)f2bf(v1.w) << 16);
      *(uint4*)&tile[c_l * 80 + i * 8] = u;
    }
  }
  __syncthreads();
  {
    int tok = tid >> 2, q = tid & 3;
    unsigned w[16];
#pragma unroll
    for (int k = 0; k < 16; ++k) {
      unsigned lo = tile[(q * 32 + 2 * k) * 80 + tok];
      unsigned hi = tile[(q * 32 + 2 * k + 1) * 80 + tok];
      w[k] = lo | (hi << 16);
    }
    ushort_t* d = xT + ((size_t)(win * 64 + tok) * 512 + kc * 128 + q * 32);
#pragma unroll
    for (int s2 = 0; s2 < 4; ++s2) {
      uint4 u; u.x = w[s2 * 4 + 0]; u.y = w[s2 * 4 + 1]; u.z = w[s2 * 4 + 2]; u.w = w[s2 * 4 + 3];
      *(uint4*)(d + s2 * 8) = u;
    }
  }
}

// ---------------- kernel 1: per-window fused QKV + 8-head attention -------------
// Grid 2304, block 512 (8 waves). 1 block/CU (122 KB LDS) -> allow ~256 VGPR.
// Weight loads batched 12-at-a-time (3 mats x 4 kk) for deep vmem pipelining.
__global__ __launch_bounds__(512, 1) void qkv_attn_k(const ushort_t* __restrict__ xT,
                                                     const ushort_t* __restrict__ wB,
                                                     const float* __restrict__ beta,
                                                     ushort_t* __restrict__ O) {
  __shared__ ushort_t xws[64 * 520];   // [token][512c], pad->520
  __shared__ ushort_t qs[2][64 * 72];  // per-head q token-major [n][d]; reused as P
  __shared__ ushort_t ks[2][64 * 72];  // per-head k token-major [m][d]
  __shared__ ushort_t vs[2][64 * 72];  // per-head v d-major [d][m]
  int win = blockIdx.x;
  int t0 = win * 64;
  int tid = threadIdx.x, lane = tid & 63, wid = tid >> 6;  // wid 0..7
  int l15 = lane & 15, l4 = lane >> 4;

  // ---- stage full window xT (64 tok x 512 ch bf16) into LDS, once ----
  {
    int token = tid >> 3, cb = (tid & 7) * 64;
    const uint4* src = (const uint4*)(xT + (size_t)(t0 + token) * 512 + cb);
    uint4* dst = (uint4*)&xws[token * 520 + cb];
#pragma unroll
    for (int s2 = 0; s2 < 8; ++s2) dst[s2] = src[s2];
  }
  __syncthreads();

  const f32x4 z = {0.f, 0.f, 0.f, 0.f};

  for (int hcc = 0; hcc < 4; ++hcc) {
    // ---- QKV for head pair hcc (out-cols [hcc*128, hcc*128+128)) ----
    f32x4 aq[4], ak[4], av[4];
#pragma unroll
    for (int i = 0; i < 4; ++i) { aq[i] = z; ak[i] = z; av[i] = z; }
    int ocol = hcc * 128 + wid * 16 + l15;
    const ushort_t* wqr = wB + (size_t)ocol * 512 + l4 * 8;
    const ushort_t* wkr = wqr + 262144;
    const ushort_t* wvr = wqr + 524288;
#pragma unroll
    for (int bb = 0; bb < 4; ++bb) {
      // batch-load 12 weight fragments (deep vmem pipeline)
      short8 bq[4], bk[4], bv[4];
#pragma unroll
      for (int j = 0; j < 4; ++j) {
        int cg = (bb * 4 + j) * 32;
        bq[j] = *(const short8*)(wqr + cg);
        bk[j] = *(const short8*)(wkr + cg);
        bv[j] = *(const short8*)(wvr + cg);
      }
#pragma unroll
      for (int j = 0; j < 4; ++j) {
        int cg = (bb * 4 + j) * 32 + l4 * 8;
#pragma unroll
        for (int nt = 0; nt < 4; ++nt) {
          short8 a = *(const short8*)&xws[(nt * 16 + l15) * 520 + cg];
          aq[nt] = __builtin_amdgcn_mfma_f32_16x16x32_bf16(a, bq[j], aq[nt], 0, 0, 0);
          ak[nt] = __builtin_amdgcn_mfma_f32_16x16x32_bf16(a, bk[j], ak[nt], 0, 0, 0);
          av[nt] = __builtin_amdgcn_mfma_f32_16x16x32_bf16(a, bv[j], av[nt], 0, 0, 0);
        }
      }
    }
    int hw = wid >> 2;            // which head of the pair this wave's cols fall in
    int dd = (wid * 16 + l15) & 63;
#pragma unroll
    for (int nt = 0; nt < 4; ++nt) {
#pragma unroll
      for (int r = 0; r < 4; ++r) {
        int n = nt * 16 + l4 * 4 + r;
        qs[hw][n * 72 + dd] = f2bf(aq[nt][r]);
        ks[hw][n * 72 + dd] = f2bf(ak[nt][r]);
      }
      uint2 u;
      u.x = (unsigned)f2bf(av[nt][0]) | ((unsigned)f2bf(av[nt][1]) << 16);
      u.y = (unsigned)f2bf(av[nt][2]) | ((unsigned)f2bf(av[nt][3]) << 16);
      *(uint2*)&vs[hw][dd * 72 + nt * 16 + l4 * 4] = u;
    }
    __syncthreads();

    // ---- attention: wave handles head h = hcc*2 + (wid>>2), rows rowg*16.. ----
    int hh = wid >> 2, rowg = wid & 3;
    int h = hcc * 2 + hh;
    f32x4 sA[4];
#pragma unroll
    for (int i = 0; i < 4; ++i) sA[i] = z;
#pragma unroll
    for (int kk = 0; kk < 2; ++kk) {
      short8 aF = *(const short8*)&qs[hh][(rowg * 16 + l15) * 72 + kk * 32 + l4 * 8];
#pragma unroll
      for (int mt = 0; mt < 4; ++mt) {
        short8 bF = *(const short8*)&ks[hh][(mt * 16 + l15) * 72 + kk * 32 + l4 * 8];
        sA[mt] = __builtin_amdgcn_mfma_f32_16x16x32_bf16(aF, bF, sA[mt], 0, 0, 0);
      }
    }
    const float* betah = beta + h * 4096;
    float p[4][4];
    float rmax[4] = {-1e30f, -1e30f, -1e30f, -1e30f};
#pragma unroll
    for (int mt = 0; mt < 4; ++mt)
#pragma unroll
      for (int r = 0; r < 4; ++r) {
        int n = rowg * 16 + l4 * 4 + r;
        float val = sA[mt][r] * 0.125f + betah[n * 64 + mt * 16 + l15];
        p[mt][r] = val;
        rmax[r] = fmaxf(rmax[r], val);
      }
#pragma unroll
    for (int m = 1; m <= 8; m <<= 1)
#pragma unroll
      for (int r = 0; r < 4; ++r) rmax[r] = fmaxf(rmax[r], __shfl_xor(rmax[r], m, 64));
    float rsum[4] = {0.f, 0.f, 0.f, 0.f};
#pragma unroll
    for (int mt = 0; mt < 4; ++mt)
#pragma unroll
      for (int r = 0; r < 4; ++r) {
        p[mt][r] = __expf(p[mt][r] - rmax[r]);
        rsum[r] += p[mt][r];
      }
#pragma unroll
    for (int m = 1; m <= 8; m <<= 1)
#pragma unroll
      for (int r = 0; r < 4; ++r) rsum[r] += __shfl_xor(rsum[r], m, 64);
    float rinv[4];
#pragma unroll
    for (int r = 0; r < 4; ++r) rinv[r] = 1.f / rsum[r];
    // P overwrites this wave's own 16 rows of qs[hh] — row-disjoint across waves,
    // and the only later reader is this wave's PV (same-wave DS ordering). No barrier.
#pragma unroll
    for (int mt = 0; mt < 4; ++mt)
#pragma unroll
      for (int r = 0; r < 4; ++r)
        qs[hh][(rowg * 16 + l4 * 4 + r) * 72 + mt * 16 + l15] = f2bf(p[mt][r] * rinv[r]);

    // ---- PV: O rows [rowg*16,+16) x 64 d ----
    f32x4 oA[4];
#pragma unroll
    for (int i = 0; i < 4; ++i) oA[i] = z;
#pragma unroll
    for (int kk = 0; kk < 2; ++kk) {
      short8 aF = *(const short8*)&qs[hh][(rowg * 16 + l15) * 72 + kk * 32 + l4 * 8];
#pragma unroll
      for (int dt = 0; dt < 4; ++dt) {
        short8 bF = *(const short8*)&vs[hh][(dt * 16 + l15) * 72 + kk * 32 + l4 * 8];
        oA[dt] = __builtin_amdgcn_mfma_f32_16x16x32_bf16(aF, bF, oA[dt], 0, 0, 0);
      }
    }
#pragma unroll
    for (int dt = 0; dt < 4; ++dt)
#pragma unroll
      for (int r = 0; r < 4; ++r) {
        int n = rowg * 16 + l4 * 4 + r;
        O[(size_t)(t0 + n) * 512 + h * 64 + dt * 16 + l15] = f2bf(oA[dt][r]);
      }
    __syncthreads();  // before next head pair overwrites qs/ks/vs
  }
}

// ---------------- kernel 3: proj GEMM 64x256 tiles; full-line fp32 stores -------
// M=64 wo rows (mm 0..7), N=256 tokens = 4 ww-consecutive windows (nn).
__global__ __launch_bounds__(256) void proj_k3(const ushort_t* __restrict__ O,
                                               const ushort_t* __restrict__ woB,
                                               const float* __restrict__ bo,
                                               float* __restrict__ out) {
  __shared__ __align__(16) char smem_raw[64 * 72 * 2 + 256 * 72 * 2];  // 46080 B
  ushort_t* As = (ushort_t*)smem_raw;            // [64][72]
  ushort_t* Bs = (ushort_t*)smem_raw + 64 * 72;  // [256][72]
  float* Ct = (float*)smem_raw;                  // [64][132] epilogue (33792 B)
  int bid = blockIdx.x;
  int cwg = gridDim.x >> 3;
  int wg = (bid & 7) * cwg + (bid >> 3);
  int nn = wg >> 3, mm = wg & 7;                 // consecutive wg share B-tile
  int tid = threadIdx.x, lane = tid & 63, wid = tid >> 6;  // wid = window-in-tile
  int l15 = lane & 15, l4 = lane >> 4;
  const ushort_t* Asrc = woB + (size_t)(mm * 64) * 512;
  const ushort_t* Bsrc = O + (size_t)(nn * 256) * 512;

  const f32x4 z = {0.f, 0.f, 0.f, 0.f};
  f32x4 acc[4][4];
#pragma unroll
  for (int i = 0; i < 4; ++i)
#pragma unroll
    for (int j = 0; j < 4; ++j) acc[i][j] = z;

  int arow[2], aslot[2];
#pragma unroll
  for (int c = 0; c < 2; ++c) { int u = c * 256 + tid; arow[c] = u >> 3; aslot[c] = u & 7; }
  int brow[8], bslot[8];
#pragma unroll
  for (int c = 0; c < 8; ++c) { int u = c * 256 + tid; brow[c] = u >> 3; bslot[c] = u & 7; }

  for (int ks = 0; ks < 8; ++ks) {
    int ko = ks * 64;
    uint4 ta[2], tb[8];
#pragma unroll
    for (int c = 0; c < 2; ++c)
      ta[c] = *(const uint4*)&Asrc[(size_t)arow[c] * 512 + ko + aslot[c] * 8];
#pragma unroll
    for (int c = 0; c < 8; ++c)
      tb[c] = *(const uint4*)&Bsrc[(size_t)brow[c] * 512 + ko + bslot[c] * 8];
    __syncthreads();
#pragma unroll
    for (int c = 0; c < 2; ++c) *(uint4*)&As[arow[c] * 72 + aslot[c] * 8] = ta[c];
#pragma unroll
    for (int c = 0; c < 8; ++c) *(uint4*)&Bs[brow[c] * 72 + bslot[c] * 8] = tb[c];
    __syncthreads();
#pragma unroll
    for (int kk = 0; kk < 2; ++kk) {
      short8 aF[4], bF[4];
#pragma unroll
      for (int mi = 0; mi < 4; ++mi)
        aF[mi] = *(const short8*)&As[(mi * 16 + l15) * 72 + kk * 32 + l4 * 8];
#pragma unroll
      for (int ni = 0; ni < 4; ++ni)
        bF[ni] = *(const short8*)&Bs[(wid * 64 + ni * 16 + l15) * 72 + kk * 32 + l4 * 8];
#pragma unroll
      for (int mi = 0; mi < 4; ++mi)
#pragma unroll
        for (int ni = 0; ni < 4; ++ni)
          acc[mi][ni] = __builtin_amdgcn_mfma_f32_16x16x32_bf16(aF[mi], bF[ni], acc[mi][ni], 0, 0, 0);
    }
  }
  // ---- epilogue: 2 passes over i-halves; LDS [o][ (i&3)*32 + w*8 + j ] fp32 ----
#pragma unroll
  for (int p = 0; p < 2; ++p) {
    __syncthreads();
#pragma unroll
    for (int mi = 0; mi < 4; ++mi)
#pragma unroll
      for (int nq = 0; nq < 2; ++nq)
#pragma unroll
        for (int rr = 0; rr < 4; ++rr) {
          int o = mi * 16 + l4 * 4 + rr;
          int i3 = nq * 2 + (l15 >> 3);
          int col = i3 * 32 + wid * 8 + (l15 & 7);
          Ct[o * 132 + col] = acc[mi][p * 2 + nq][rr];
        }
    __syncthreads();
#pragma unroll
    for (int it = 0; it < 8; ++it) {
      int cidx = it * 256 + tid;
      int o_l = cidx >> 5, c4 = cidx & 31;
      float4 v = *(const float4*)&Ct[o_l * 132 + c4 * 4];
      int o = mm * 64 + o_l;
      float bias = bo[o];
      int w = (c4 & 7) >> 1, j = (c4 & 1) * 4, i = p * 4 + (c4 >> 3);
      int win = nn * 4 + w;
      int b = win / 576, rem = win % 576, wh = rem / 24, ww = rem % 24;
      size_t addr = (((size_t)b * 512 + o) * 192 + wh * 8 + i) * 192 + ww * 8 + j;
      float4 r;
      r.x = v.x + bias; r.y = v.y + bias; r.z = v.z + bias; r.w = v.w + bias;
      *(float4*)&out[addr] = r;
    }
  }
}

extern "C" void kernel_launch(void* const* d_in, const int* in_sizes, int n_in,
                              void* d_out, int out_size, void* d_ws, size_t ws_size,
                              hipStream_t stream) {
  const float* x    = (const float*)d_in[0];
  const float* wq   = (const float*)d_in[1];
  const float* wk   = (const float*)d_in[2];
  const float* wv   = (const float*)d_in[3];
  const float* wo   = (const float*)d_in[4];
  const float* bo   = (const float*)d_in[5];
  const float* beta = (const float*)d_in[6];

  // layout in d_ws (ws >= 578 MiB confirmed): wB 2 MiB | xT 151 MB | O 151 MB
  ushort_t* wB = (ushort_t*)d_ws;
  ushort_t* xT = (ushort_t*)((char*)d_ws + (size_t)2097152);
  ushort_t* O  = (ushort_t*)((char*)d_ws + (size_t)2097152 + (size_t)147456 * 1024);

  cvt_w_k<<<1024, 256, 0, stream>>>(wq, wk, wv, wo, wB);
  xpose_k<<<2304 * 4, 256, 0, stream>>>(x, xT);
  qkv_attn_k<<<2304, 512, 0, stream>>>(xT, wB, beta, O);
  proj_k3<<<(147456 / 256) * 8, 256, 0, stream>>>(O, wB + 3 * 262144, bo, (float*)d_out);
}